// Round 5
// baseline (127.767 us; speedup 1.0000x reference)
//
#include <hip/hip_runtime.h>

typedef unsigned short ushort_t;
typedef __attribute__((ext_vector_type(8))) short bfrag;
typedef __attribute__((ext_vector_type(4))) float f4;

// B=4, D=256, H=W=64, num_levels=4, radius=4
#define NB 4
#define ND 256
#define NH 64
#define NW 64
#define NQ (NH * NW)            // 4096 queries per batch
#define MPAD 5632               // 22 * 256 rows of pooled-f2 features (5440 real)
#define NLVL 4
#define NCH (NLVL * 81)

__device__ __forceinline__ float bf2f(ushort_t u) {
    return __uint_as_float(((unsigned)u) << 16);
}
__device__ __forceinline__ ushort_t f2bf(float f) {
    unsigned u = __float_as_uint(f);
    unsigned r = (u + 0x7fffu + ((u >> 16) & 1u)) >> 16;
    return (ushort_t)r;
}

__device__ __forceinline__ void gload_lds16(const void* g, void* l) {
    __builtin_amdgcn_global_load_lds(
        (const __attribute__((address_space(1))) unsigned int*)g,
        (__attribute__((address_space(3))) unsigned int*)l, 16, 0, 0);
}

// ---------- kernel 1: transpose [b][256][4096] f32 -> [b][n][256] bf16 (opt. scale) ----------
__global__ __launch_bounds__(256) void transpose_cvt(
    const float* __restrict__ in, ushort_t* __restrict__ outp,
    size_t in_bstride, size_t out_bstride, float scale)
{
    __shared__ float tile[64][65];
    const int tid = threadIdx.x;
    const int n0 = blockIdx.x * 64, d0 = blockIdx.y * 64, b = blockIdx.z;
    const float* ib = in + (size_t)b * in_bstride;
    ushort_t* ob = outp + (size_t)b * out_bstride;
    const int nl = tid & 63, dg = tid >> 6;
#pragma unroll
    for (int i = 0; i < 16; i++) {
        int dl = dg + i * 4;
        tile[dl][nl] = ib[(size_t)(d0 + dl) * NQ + n0 + nl];
    }
    __syncthreads();
    const int dl = tid & 63, ng = tid >> 6;
#pragma unroll
    for (int i = 0; i < 16; i++) {
        int nn = ng + i * 4;
        ob[(size_t)(n0 + nn) * ND + d0 + dl] = f2bf(tile[dl][nn] * scale);
    }
}

// ---------- kernel 2: avg-pool 2x2 in [m][d] bf16 layout (cascade) ----------
__global__ void pool_kernel(ushort_t* __restrict__ Ball, int Wlo, int in_off, int out_off)
{
    int t = blockIdx.x * 256 + threadIdx.x;
    int d = t & 255;
    int rest = t >> 8;
    int Nl = Wlo * Wlo;
    int m = rest % Nl;
    int b = rest / Nl;
    if (b >= NB) return;
    int y = m / Wlo, x = m - y * Wlo;
    int Wi = Wlo * 2;
    const ushort_t* src = Ball + (size_t)b * MPAD * ND;
    float s = 0.f;
#pragma unroll
    for (int iy = 0; iy < 2; iy++)
#pragma unroll
        for (int ix = 0; ix < 2; ix++)
            s += bf2f(src[(size_t)(in_off + (2 * y + iy) * Wi + (2 * x + ix)) * ND + d]);
    Ball[(size_t)b * MPAD * ND + (size_t)(out_off + m) * ND + d] = f2bf(s * 0.25f);
}

// ---------- kernel 2b: per-(batch,level,query) integer window base table ----------
__global__ void make_tbl(const float* __restrict__ coords, int* __restrict__ tbl)
{
    int t = blockIdx.x * 256 + threadIdx.x;     // b*4096 + q
    int b = t >> 12, q = t & 4095;
    float cx = coords[((size_t)b * 2 + 0) * NQ + q];
    float cy = coords[((size_t)b * 2 + 1) * NQ + q];
#pragma unroll
    for (int lvl = 0; lvl < 4; lvl++) {
        float s = 1.0f / (float)(1 << lvl);
        int x0 = (int)floorf(cx * s);
        int y0 = (int)floorf(cy * s);
        tbl[((b * 4 + lvl) << 12) + q] = (x0 & 0xffff) | (y0 << 16);
    }
}

// ---------- kernel 3: 256x256-tile, 8-wave, 4-slot pipelined bf16 MFMA GEMM ----------
// grid.x = 1408 = 4 batches * 16 M-tiles * 22 N-tiles, XCD-swizzled
__global__ __launch_bounds__(512, 2) void gemm_corr(
    const ushort_t* __restrict__ A,     // [NB][4096][256] bf16 (pre-scaled by 1/16)
    const ushort_t* __restrict__ Bm,    // [NB][MPAD][256] bf16
    ushort_t* __restrict__ compact,     // [NB][4096][400] bf16
    const int* __restrict__ tbl)        // [NB][4][4096] packed (x0,y0)
{
    // 4 K-tile slots: A[s]: 256x32 bf16 = 8192 ushorts at s*8192; B at 32768 + s*8192
    __shared__ ushort_t SM[65536];      // 128 KiB

    // bijective XCD-chunk swizzle: 1408 = 8 * 176
    const int l   = blockIdx.x;
    const int wg  = (l & 7) * 176 + (l >> 3);
    const int z   = wg / 352;
    const int rem = wg - z * 352;
    const int by  = rem / 22;
    const int bxt = rem - by * 22;

    int lvl, lbase;
    if (bxt < 16)      { lvl = 0; lbase = bxt * 256; }
    else if (bxt < 20) { lvl = 1; lbase = (bxt - 16) * 256; }
    else if (bxt < 21) { lvl = 2; lbase = 0; }
    else               { lvl = 3; lbase = 0; }      // 64 real cols + 192 pad
    const int mbase = bxt * 256;

    const int tid  = threadIdx.x;
    const int lane = tid & 63;
    const int wv   = tid >> 6;       // 0..7
    const int wm   = wv >> 2;        // M-half (0,1): rows wm*128..+128
    const int wn   = wv & 3;         // N-quarter: cols wn*64..+64

    const ushort_t* Ab = A  + ((size_t)z * NQ   + (size_t)by * 256) * ND;
    const ushort_t* Bb = Bm + ((size_t)z * MPAD + (size_t)mbase) * ND;

    // staging: thread t covers rows {t>>2, 128+(t>>2)}, 16B chunk (t&3), swizzled
    const int sr = tid >> 2;
    const int sc = (tid & 3) ^ ((tid >> 3) & 3);     // inverse-swizzled source chunk
    const ushort_t* sA0 = Ab + (size_t)sr * ND + sc * 8;
    const ushort_t* sA1 = sA0 + (size_t)128 * ND;
    const ushort_t* sB0 = Bb + (size_t)sr * ND + sc * 8;
    const ushort_t* sB1 = sB0 + (size_t)128 * ND;

#define STAGE_A(s, T) { gload_lds16(sA0 + (T) * 32, &SM[(s) * 8192 + tid * 8]);          \
                        gload_lds16(sA1 + (T) * 32, &SM[(s) * 8192 + 4096 + tid * 8]); }
#define STAGE_B(s, T) { gload_lds16(sB0 + (T) * 32, &SM[32768 + (s) * 8192 + tid * 8]);  \
                        gload_lds16(sB1 + (T) * 32, &SM[32768 + (s) * 8192 + 4096 + tid * 8]); }

    // fragment reads (swizzled): row r, chunk (lane>>4) ^ ((r>>1)&3); r = base + ln15
    const int ln15 = lane & 15;
    const int kch  = (lane >> 4) ^ ((ln15 >> 1) & 3);
    const int aoff = (wm * 128 + ln15) * 32 + kch * 8;
    const int boff = 32768 + (wn * 64 + ln15) * 32 + kch * 8;

    f4 acc[8][4] = {};

    // prologue: stage K-tiles 0,1,2 into slots 0,1,2
    STAGE_A(0, 0); STAGE_B(0, 0);
    STAGE_A(1, 1); STAGE_B(1, 1);
    STAGE_A(2, 2); STAGE_B(2, 2);

#pragma unroll
    for (int T = 0; T < 8; ++T) {
        const int s = T & 3;
        if (T < 6)       { asm volatile("s_waitcnt vmcnt(8)" ::: "memory"); }
        else if (T == 6) { asm volatile("s_waitcnt vmcnt(4)" ::: "memory"); }
        else             { asm volatile("s_waitcnt vmcnt(0)" ::: "memory"); }
        __builtin_amdgcn_s_barrier();            // slot s fully staged (all waves)
        asm volatile("" ::: "memory");

        bfrag a[4], b[4];
        // ---- phase 0: read A mi=0..3 + all B, stage A of K-tile T+3, MFMA quad 0 ----
#pragma unroll
        for (int mi = 0; mi < 4; mi++)
            a[mi] = *reinterpret_cast<const bfrag*>(&SM[s * 8192 + aoff + mi * 512]);
#pragma unroll
        for (int ni = 0; ni < 4; ni++)
            b[ni] = *reinterpret_cast<const bfrag*>(&SM[s * 8192 + boff + ni * 512]);
        if (T < 5) STAGE_A((T + 3) & 3, T + 3);
        __builtin_amdgcn_s_setprio(1);
#pragma unroll
        for (int mi = 0; mi < 4; mi++)
#pragma unroll
            for (int ni = 0; ni < 4; ni++)
                acc[mi][ni] = __builtin_amdgcn_mfma_f32_16x16x32_bf16(
                    a[mi], b[ni], acc[mi][ni], 0, 0, 0);
        __builtin_amdgcn_s_setprio(0);

        // ---- phase 1: read A mi=4..7, stage B of K-tile T+3, MFMA quad 1 ----
#pragma unroll
        for (int mi = 0; mi < 4; mi++)
            a[mi] = *reinterpret_cast<const bfrag*>(&SM[s * 8192 + aoff + (mi + 4) * 512]);
        if (T < 5) STAGE_B((T + 3) & 3, T + 3);
        __builtin_amdgcn_s_setprio(1);
#pragma unroll
        for (int mi = 0; mi < 4; mi++)
#pragma unroll
            for (int ni = 0; ni < 4; ni++)
                acc[mi + 4][ni] = __builtin_amdgcn_mfma_f32_16x16x32_bf16(
                    a[mi], b[ni], acc[mi + 4][ni], 0, 0, 0);
        __builtin_amdgcn_s_setprio(0);

        __builtin_amdgcn_s_barrier();            // all reads of slot s done
        asm volatile("" ::: "memory");           // (slot s is overwritten at T+1)
    }
#undef STAGE_A
#undef STAGE_B

    // ---- compacted epilogue: keep only dots inside some query's 10x10 window ----
    const int qbase = by * 256 + wm * 128 + ((lane >> 4) << 2);
    const int col0  = lbase + wn * 64 + ln15;    // within-level col of ni=0
    const unsigned Wm1 = (64u >> lvl) - 1u;
    const int logW     = 6 - lvl;
    const int* tb      = tbl + (((size_t)z * 4 + lvl) << 12);
    ushort_t* cmp      = compact + (size_t)z * NQ * 400 + lvl * 100;

    int ux[4], vy[4];
#pragma unroll
    for (int ni = 0; ni < 4; ni++) {
        int cl = col0 + ni * 16;
        bool valid = !(bxt == 21 && cl >= 64);   // discard pad cols
        ux[ni] = valid ? (int)(cl & Wm1) + 4 : (1 << 20);
        vy[ni] = (cl >> logW) + 4;
    }

#pragma unroll
    for (int mi = 0; mi < 8; mi++)
#pragma unroll
        for (int j = 0; j < 4; j++) {
            int q  = qbase + mi * 16 + j;
            int xy = tb[q];
            int x0 = xy & 0xffff, y0 = xy >> 16;
#pragma unroll
            for (int ni = 0; ni < 4; ni++) {
                unsigned u = (unsigned)(ux[ni] - x0);
                unsigned v = (unsigned)(vy[ni] - y0);
                if (u < 10u && v < 10u)
                    cmp[(size_t)q * 400 + v * 10 + u] = f2bf(acc[mi][ni][j]);
            }
        }
}

// ---------- kernel 4: bilinear sampling from the compact window buffer ----------
__global__ __launch_bounds__(256) void sample_kernel(
    const ushort_t* __restrict__ compact,  // [NB][4096][400] bf16
    const float* __restrict__ coords,
    float* __restrict__ out)               // [NB][324][64][64] f32
{
    __shared__ int   X0s[16], Y0s[16];
    __shared__ float wxs[16], wys[16];
    __shared__ float Dl[16 * 101];
    const int tid = threadIdx.x;
    const int g   = blockIdx.x;
    const int lvl = blockIdx.y;
    const int b   = blockIdx.z;
    const int Wl  = NW >> lvl;

    if (tid < 16) {
        int q = g * 16 + tid;
        float cx = coords[(size_t)(b * 2 + 0) * NQ + q];
        float cy = coords[(size_t)(b * 2 + 1) * NQ + q];
        float s = 1.0f / (float)(1 << lvl);
        float xl = cx * s, yl = cy * s;
        float fx = floorf(xl), fy = floorf(yl);
        X0s[tid] = (int)fx;
        Y0s[tid] = (int)fy;
        wxs[tid] = xl - fx;
        wys[tid] = yl - fy;
    }
    __syncthreads();

#pragma unroll
    for (int r = 0; r < 7; r++) {
        int e = r * 256 + tid;
        if (e < 16 * 100) {
            int qi = e / 100;
            int el = e - qi * 100;
            int v = el / 10;
            int u = el - v * 10;
            int xx = X0s[qi] - 4 + u;
            int yy = Y0s[qi] - 4 + v;
            float val = 0.f;
            if ((unsigned)xx < (unsigned)Wl && (unsigned)yy < (unsigned)Wl)
                val = bf2f(compact[((size_t)b * NQ + g * 16 + qi) * 400
                                   + lvl * 100 + el]);
            Dl[qi * 101 + el] = val;
        }
    }
    __syncthreads();

#pragma unroll
    for (int r = 0; r < 6; r++) {
        int e = r * 256 + tid;
        if (e < 16 * 81) {
            int qi = e & 15;
            int c = e >> 4;
            int i = c / 9;            // x-offset grid index
            int j = c - i * 9;        // y-offset grid index
            float wx = wxs[qi], wy = wys[qi];
            const float* dq = &Dl[qi * 101];
            float d00 = dq[j * 10 + i];
            float d10 = dq[j * 10 + i + 1];
            float d01 = dq[(j + 1) * 10 + i];
            float d11 = dq[(j + 1) * 10 + i + 1];
            float vx0 = d00 + wx * (d10 - d00);
            float vx1 = d01 + wx * (d11 - d01);
            float val = vx0 + wy * (vx1 - vx0);
            out[((size_t)b * NCH + lvl * 81 + c) * NQ + g * 16 + qi] = val;
        }
    }
}

extern "C" void kernel_launch(void* const* d_in, const int* in_sizes, int n_in,
                              void* d_out, int out_size, void* d_ws, size_t ws_size,
                              hipStream_t stream)
{
    const float* fmap1  = (const float*)d_in[0];
    const float* fmap2  = (const float*)d_in[1];
    const float* coords = (const float*)d_in[2];
    float* out = (float*)d_out;

    char* ws = (char*)d_ws;
    const size_t A_BYTES   = (size_t)NB * NQ * ND * 2;     //  8.4 MB
    const size_t B_BYTES   = (size_t)NB * MPAD * ND * 2;   // 11.5 MB
    const size_t CMP_BYTES = (size_t)NB * NQ * 400 * 2;    // 13.1 MB
    ushort_t* Abf  = (ushort_t*)ws;
    ushort_t* Ball = (ushort_t*)(ws + A_BYTES);
    ushort_t* cmp  = (ushort_t*)(ws + A_BYTES + B_BYTES);
    int*      tbl  = (int*)(ws + A_BYTES + B_BYTES + CMP_BYTES);

    transpose_cvt<<<dim3(64, 4, NB), 256, 0, stream>>>(
        fmap1, Abf, (size_t)ND * NQ, (size_t)NQ * ND, 0.0625f);
    transpose_cvt<<<dim3(64, 4, NB), 256, 0, stream>>>(
        fmap2, Ball, (size_t)ND * NQ, (size_t)MPAD * ND, 1.0f);

    pool_kernel<<<(NB * 1024 * ND) / 256, 256, 0, stream>>>(Ball, 32, 0,    4096);
    pool_kernel<<<(NB * 256  * ND) / 256, 256, 0, stream>>>(Ball, 16, 4096, 5120);
    pool_kernel<<<(NB * 64   * ND) / 256, 256, 0, stream>>>(Ball, 8,  5120, 5376);

    make_tbl<<<(NB * NQ) / 256, 256, 0, stream>>>(coords, tbl);

    gemm_corr<<<dim3(16 * 22 * NB), 512, 0, stream>>>(Abf, Ball, cmp, tbl);

    sample_kernel<<<dim3(256, NLVL, NB), 256, 0, stream>>>(cmp, coords, out);
}

// Round 7
// 97.710 us; speedup vs baseline: 1.3076x; 1.3076x over previous
//
#include <hip/hip_runtime.h>

typedef unsigned short ushort_t;
typedef __attribute__((ext_vector_type(8))) short bfrag;
typedef __attribute__((ext_vector_type(4))) float f4;

// B=4, D=256, H=W=64, num_levels=4, radius=4
#define NB 4
#define ND 256
#define NH 64
#define NW 64
#define NQ (NH * NW)            // 4096 queries per batch
#define MPAD 5504               // 43 * 128 rows of pooled-f2 features
#define NLVL 4
#define NCH (NLVL * 81)

__device__ __forceinline__ float bf2f(ushort_t u) {
    return __uint_as_float(((unsigned)u) << 16);
}
__device__ __forceinline__ ushort_t f2bf(float f) {
    unsigned u = __float_as_uint(f);
    unsigned r = (u + 0x7fffu + ((u >> 16) & 1u)) >> 16;
    return (ushort_t)r;
}

__device__ __forceinline__ void gload_lds16(const void* g, void* l) {
    __builtin_amdgcn_global_load_lds(
        (const __attribute__((address_space(1))) unsigned int*)g,
        (__attribute__((address_space(3))) unsigned int*)l, 16, 0, 0);
}

// ---------- kernel 1: transpose [b][256][4096] f32 -> [b][n][256] bf16 (opt. scale) ----------
__global__ __launch_bounds__(256) void transpose_cvt(
    const float* __restrict__ in, ushort_t* __restrict__ outp,
    size_t in_bstride, size_t out_bstride, float scale)
{
    __shared__ float tile[64][65];
    const int tid = threadIdx.x;
    const int n0 = blockIdx.x * 64, d0 = blockIdx.y * 64, b = blockIdx.z;
    const float* ib = in + (size_t)b * in_bstride;
    ushort_t* ob = outp + (size_t)b * out_bstride;
    const int nl = tid & 63, dg = tid >> 6;
#pragma unroll
    for (int i = 0; i < 16; i++) {
        int dl = dg + i * 4;
        tile[dl][nl] = ib[(size_t)(d0 + dl) * NQ + n0 + nl];
    }
    __syncthreads();
    const int dl = tid & 63, ng = tid >> 6;
#pragma unroll
    for (int i = 0; i < 16; i++) {
        int nn = ng + i * 4;
        ob[(size_t)(n0 + nn) * ND + d0 + dl] = f2bf(tile[dl][nn] * scale);
    }
}

// ---------- kernel 2: avg-pool 2x2 in [m][d] bf16 layout (cascade) ----------
__global__ void pool_kernel(ushort_t* __restrict__ Ball, int Wlo, int in_off, int out_off)
{
    int t = blockIdx.x * 256 + threadIdx.x;
    int d = t & 255;
    int rest = t >> 8;
    int Nl = Wlo * Wlo;
    int m = rest % Nl;
    int b = rest / Nl;
    if (b >= NB) return;
    int y = m / Wlo, x = m - y * Wlo;
    int Wi = Wlo * 2;
    const ushort_t* src = Ball + (size_t)b * MPAD * ND;
    float s = 0.f;
#pragma unroll
    for (int iy = 0; iy < 2; iy++)
#pragma unroll
        for (int ix = 0; ix < 2; ix++)
            s += bf2f(src[(size_t)(in_off + (2 * y + iy) * Wi + (2 * x + ix)) * ND + d]);
    Ball[(size_t)b * MPAD * ND + (size_t)(out_off + m) * ND + d] = f2bf(s * 0.25f);
}

// ---------- kernel 2b: per-(batch,level,query) integer window base table ----------
__global__ void make_tbl(const float* __restrict__ coords, int* __restrict__ tbl)
{
    int t = blockIdx.x * 256 + threadIdx.x;     // b*4096 + q
    int b = t >> 12, q = t & 4095;
    float cx = coords[((size_t)b * 2 + 0) * NQ + q];
    float cy = coords[((size_t)b * 2 + 1) * NQ + q];
#pragma unroll
    for (int lvl = 0; lvl < 4; lvl++) {
        float s = 1.0f / (float)(1 << lvl);
        int x0 = (int)floorf(cx * s);
        int y0 = (int)floorf(cy * s);
        tbl[((b * 4 + lvl) << 12) + q] = (x0 & 0xffff) | (y0 << 16);
    }
}

// ---------- kernel 3: 3-buffer (prefetch-distance-2) bf16 MFMA GEMM ----------
// grid.x = 5504 = 4 batches * 32 n-tiles * 43 m-tiles, XCD-swizzled
__global__ __launch_bounds__(256) void gemm_corr(
    const ushort_t* __restrict__ A,     // [NB][4096][256] bf16 (pre-scaled by 1/16)
    const ushort_t* __restrict__ Bm,    // [NB][MPAD][256] bf16
    ushort_t* __restrict__ compact,     // [NB][4096][400] bf16
    const int* __restrict__ tbl)        // [NB][4][4096] packed (x0,y0)
{
    __shared__ ushort_t As[3][128 * 32];
    __shared__ ushort_t Bs[3][128 * 32];

    // bijective XCD-chunk swizzle: 5504 = 8 * 688
    const int l   = blockIdx.x;
    const int wg  = (l & 7) * 688 + (l >> 3);
    const int z   = wg / 1376;
    const int rem = wg - z * 1376;
    const int by  = rem / 43;
    const int bxt = rem - by * 43;

    int lvl, mbase;
    if (bxt < 32)      { lvl = 0; mbase = bxt * 128; }
    else if (bxt < 40) { lvl = 1; mbase = 4096 + (bxt - 32) * 128; }
    else if (bxt < 42) { lvl = 2; mbase = 5120 + (bxt - 40) * 128; }
    else               { lvl = 3; mbase = 5376; }

    const int tid  = threadIdx.x;
    const int lane = tid & 63;
    const int wv   = tid >> 6;
    const int wr   = wv >> 1, wc = wv & 1;

    const ushort_t* Ab = A  + ((size_t)z * NQ   + (size_t)by * 128) * ND;
    const ushort_t* Bb = Bm + ((size_t)z * MPAD + (size_t)mbase) * ND;

    f4 acc[4][4] = {};
    const int r0 = tid >> 2;          // staged row within 64-row half
    const int c8 = tid & 3;           // dest 16B slot within the 32-wide K slice
    const int s0 = (r0 >> 1) & 3;     // XOR swizzle key (same for row r0 and 64+r0)

    // rule #21: linear LDS dest + inverse-swizzled global SOURCE + swizzled READ
#define STAGE(buf, kk) {                                                                  \
    gload_lds16(Ab + (size_t)r0 * ND + (kk) + (c8 ^ s0) * 8,        &As[buf][tid * 8]);   \
    gload_lds16(Ab + (size_t)(64 + r0) * ND + (kk) + (c8 ^ s0) * 8, &As[buf][(256+tid)*8]);\
    gload_lds16(Bb + (size_t)r0 * ND + (kk) + (c8 ^ s0) * 8,        &Bs[buf][tid * 8]);   \
    gload_lds16(Bb + (size_t)(64 + r0) * ND + (kk) + (c8 ^ s0) * 8, &Bs[buf][(256+tid)*8]);}

    const int ln15 = lane & 15;
    const int sl = (ln15 >> 1) & 3;              // read-side swizzle key
    const int kch = ((lane >> 4) ^ sl) * 8;      // swizzled 8-elem slot

    STAGE(0, 0);
    STAGE(1, 32);
    STAGE(2, 64);

#pragma unroll
    for (int t = 0; t < 8; ++t) {
        const int cur = t % 3;
        // needed slot's loads are 2 K-steps old -> near-zero stall
        if (t < 6)       { asm volatile("s_waitcnt vmcnt(8)" ::: "memory"); }
        else if (t == 6) { asm volatile("s_waitcnt vmcnt(4)" ::: "memory"); }
        else             { asm volatile("s_waitcnt vmcnt(0)" ::: "memory"); }
        __builtin_amdgcn_s_barrier();        // #1: slot `cur` fully staged
        asm volatile("" ::: "memory");

        bfrag a[4], bb[4];
#pragma unroll
        for (int mi = 0; mi < 4; mi++)
            a[mi] = *reinterpret_cast<const bfrag*>(
                &As[cur][(wr * 64 + mi * 16 + ln15) * 32 + kch]);
#pragma unroll
        for (int ni = 0; ni < 4; ni++)
            bb[ni] = *reinterpret_cast<const bfrag*>(
                &Bs[cur][(wc * 64 + ni * 16 + ln15) * 32 + kch]);

        if (t < 5) {
            __builtin_amdgcn_sched_barrier(0);                    // pin ds_reads above
            asm volatile("s_waitcnt lgkmcnt(0)" ::: "memory");    // my reads complete
            __builtin_amdgcn_s_barrier();     // #2: all waves done reading slot `cur`
            asm volatile("" ::: "memory");
            STAGE(cur, (t + 3) * 32);         // overwrite slot `cur` with K-step t+3
        }

#pragma unroll
        for (int mi = 0; mi < 4; mi++)
#pragma unroll
            for (int ni = 0; ni < 4; ni++)
                acc[mi][ni] = __builtin_amdgcn_mfma_f32_16x16x32_bf16(
                    a[mi], bb[ni], acc[mi][ni], 0, 0, 0);
    }
#undef STAGE

    // ---- compacted epilogue, geometry-aware per level ----
    // col(ni) within level = (mbase - lvl_offset) + wc*64 + ln15 + 16*ni
    const int row_base = by * 128 + wr * 64 + ((lane >> 4) << 2);
    const int* tb      = tbl + (((size_t)z * 4 + lvl) << 12);
    ushort_t* cmp      = compact + (size_t)z * NQ * 400 + lvl * 100;

    // generic per-query iterator: body(mi, j, x0, y0, qb)
    auto for_q = [&](auto body) {
#pragma unroll
        for (int mi = 0; mi < 4; mi++) {
            const int q0 = row_base + mi * 16;
            const int4 xy4 = *reinterpret_cast<const int4*>(&tb[q0]);
            const int xys[4] = {xy4.x, xy4.y, xy4.z, xy4.w};
#pragma unroll
            for (int j = 0; j < 4; j++) {
                const int xy = xys[j];
                body(mi, j, xy & 0xffff, xy >> 16, (size_t)(q0 + j) * 400);
            }
        }
    };

    if (lvl == 0) {
        const int yfix = bxt * 2 + wc;           // y constant per thread
        for_q([&](int mi, int j, int x0, int y0, size_t qb) {
            unsigned v = (unsigned)(yfix - y0 + 4);
            if (v < 10u) {
                size_t vb = qb + v * 10;
#pragma unroll
                for (int ni = 0; ni < 4; ni++) {
                    unsigned u = (unsigned)(ln15 + 16 * ni + 4 - x0);
                    if (u < 10u) cmp[vb + u] = f2bf(acc[mi][ni][j]);
                }
            }
        });
    } else if (lvl == 1) {
        const int ybase = (bxt - 32) * 4 + wc * 2;
        for_q([&](int mi, int j, int x0, int y0, size_t qb) {
            unsigned u0 = (unsigned)(ln15 + 4 - x0), u1 = u0 + 16u;
            unsigned v0 = (unsigned)(ybase - y0 + 4), v1 = v0 + 1u;
            if (v0 < 10u) {
                if (u0 < 10u) cmp[qb + v0 * 10 + u0] = f2bf(acc[mi][0][j]);
                if (u1 < 10u) cmp[qb + v0 * 10 + u1] = f2bf(acc[mi][1][j]);
            }
            if (v1 < 10u) {
                if (u0 < 10u) cmp[qb + v1 * 10 + u0] = f2bf(acc[mi][2][j]);
                if (u1 < 10u) cmp[qb + v1 * 10 + u1] = f2bf(acc[mi][3][j]);
            }
        });
    } else if (lvl == 2) {
        const int ybase = (bxt - 40) * 8 + wc * 4;
        for_q([&](int mi, int j, int x0, int y0, size_t qb) {
            unsigned u = (unsigned)(ln15 + 4 - x0);
            if (u < 10u) {
#pragma unroll
                for (int ni = 0; ni < 4; ni++) {
                    unsigned v = (unsigned)(ybase + ni - y0 + 4);
                    if (v < 10u) cmp[qb + v * 10 + u] = f2bf(acc[mi][ni][j]);
                }
            }
        });
    } else if (wc == 0) {                        // lvl 3: cols 64..127 are pad
        const int yb3 = ln15 >> 3;
        for_q([&](int mi, int j, int x0, int y0, size_t qb) {
            unsigned u = (unsigned)((ln15 & 7) + 4 - x0);
            if (u < 10u) {
#pragma unroll
                for (int ni = 0; ni < 4; ni++) {
                    unsigned v = (unsigned)(yb3 + 2 * ni - y0 + 4);
                    if (v < 10u) cmp[qb + v * 10 + u] = f2bf(acc[mi][ni][j]);
                }
            }
        });
    }
}

// ---------- kernel 4: bilinear sampling from the compact window buffer ----------
__global__ __launch_bounds__(256) void sample_kernel(
    const ushort_t* __restrict__ compact,  // [NB][4096][400] bf16
    const float* __restrict__ coords,
    float* __restrict__ out)               // [NB][324][64][64] f32
{
    __shared__ int   X0s[16], Y0s[16];
    __shared__ float wxs[16], wys[16];
    __shared__ float Dl[16 * 101];
    const int tid = threadIdx.x;
    const int g   = blockIdx.x;
    const int lvl = blockIdx.y;
    const int b   = blockIdx.z;
    const int Wl  = NW >> lvl;

    if (tid < 16) {
        int q = g * 16 + tid;
        float cx = coords[(size_t)(b * 2 + 0) * NQ + q];
        float cy = coords[(size_t)(b * 2 + 1) * NQ + q];
        float s = 1.0f / (float)(1 << lvl);
        float xl = cx * s, yl = cy * s;
        float fx = floorf(xl), fy = floorf(yl);
        X0s[tid] = (int)fx;
        Y0s[tid] = (int)fy;
        wxs[tid] = xl - fx;
        wys[tid] = yl - fy;
    }
    __syncthreads();

#pragma unroll
    for (int r = 0; r < 7; r++) {
        int e = r * 256 + tid;
        if (e < 16 * 100) {
            int qi = e / 100;
            int el = e - qi * 100;
            int v = el / 10;
            int u = el - v * 10;
            int xx = X0s[qi] - 4 + u;
            int yy = Y0s[qi] - 4 + v;
            float val = 0.f;
            if ((unsigned)xx < (unsigned)Wl && (unsigned)yy < (unsigned)Wl)
                val = bf2f(compact[((size_t)b * NQ + g * 16 + qi) * 400
                                   + lvl * 100 + el]);
            Dl[qi * 101 + el] = val;
        }
    }
    __syncthreads();

#pragma unroll
    for (int r = 0; r < 6; r++) {
        int e = r * 256 + tid;
        if (e < 16 * 81) {
            int qi = e & 15;
            int c = e >> 4;
            int i = c / 9;            // x-offset grid index
            int j = c - i * 9;        // y-offset grid index
            float wx = wxs[qi], wy = wys[qi];
            const float* dq = &Dl[qi * 101];
            float d00 = dq[j * 10 + i];
            float d10 = dq[j * 10 + i + 1];
            float d01 = dq[(j + 1) * 10 + i];
            float d11 = dq[(j + 1) * 10 + i + 1];
            float vx0 = d00 + wx * (d10 - d00);
            float vx1 = d01 + wx * (d11 - d01);
            float val = vx0 + wy * (vx1 - vx0);
            out[((size_t)b * NCH + lvl * 81 + c) * NQ + g * 16 + qi] = val;
        }
    }
}

extern "C" void kernel_launch(void* const* d_in, const int* in_sizes, int n_in,
                              void* d_out, int out_size, void* d_ws, size_t ws_size,
                              hipStream_t stream)
{
    const float* fmap1  = (const float*)d_in[0];
    const float* fmap2  = (const float*)d_in[1];
    const float* coords = (const float*)d_in[2];
    float* out = (float*)d_out;

    char* ws = (char*)d_ws;
    const size_t A_BYTES   = (size_t)NB * NQ * ND * 2;     //  8.4 MB
    const size_t B_BYTES   = (size_t)NB * MPAD * ND * 2;   // 11.3 MB
    const size_t CMP_BYTES = (size_t)NB * NQ * 400 * 2;    // 13.1 MB
    ushort_t* Abf  = (ushort_t*)ws;
    ushort_t* Ball = (ushort_t*)(ws + A_BYTES);
    ushort_t* cmp  = (ushort_t*)(ws + A_BYTES + B_BYTES);
    int*      tbl  = (int*)(ws + A_BYTES + B_BYTES + CMP_BYTES);

    transpose_cvt<<<dim3(64, 4, NB), 256, 0, stream>>>(
        fmap1, Abf, (size_t)ND * NQ, (size_t)NQ * ND, 0.0625f);
    transpose_cvt<<<dim3(64, 4, NB), 256, 0, stream>>>(
        fmap2, Ball, (size_t)ND * NQ, (size_t)MPAD * ND, 1.0f);

    pool_kernel<<<(NB * 1024 * ND) / 256, 256, 0, stream>>>(Ball, 32, 0,    4096);
    pool_kernel<<<(NB * 256  * ND) / 256, 256, 0, stream>>>(Ball, 16, 4096, 5120);
    pool_kernel<<<(NB * 64   * ND) / 256, 256, 0, stream>>>(Ball, 8,  5120, 5376);

    make_tbl<<<(NB * NQ) / 256, 256, 0, stream>>>(coords, tbl);

    gemm_corr<<<dim3(43 * 32 * NB), 256, 0, stream>>>(Abf, Ball, cmp, tbl);

    sample_kernel<<<dim3(256, NLVL, NB), 256, 0, stream>>>(cmp, coords, out);
}